// Round 1
// baseline (1677.435 us; speedup 1.0000x reference)
//
#include <hip/hip_runtime.h>
#include <hip/hip_bf16.h>

#define D_MODEL 4096
#define D_FF    11008
#define NTOK    4096   // 2 * 2048 tokens

typedef unsigned int u32;
using f32x4   = __attribute__((ext_vector_type(4))) float;
using bf16x8  = __attribute__((ext_vector_type(8))) short;
using ushort8 = __attribute__((ext_vector_type(8))) unsigned short;
using int4v   = __attribute__((ext_vector_type(4))) int;
using float4v = __attribute__((ext_vector_type(4))) float;

__device__ __forceinline__ unsigned short bf16_rn(float f) {
    u32 u = __builtin_bit_cast(u32, f);
    u += 0x7FFFu + ((u >> 16) & 1u);
    return (unsigned short)(u >> 16);
}
// int in [-127,127] -> bf16 is exact; truncation of fp32 bits suffices
__device__ __forceinline__ unsigned short bf16_from_int(int v) {
    float f = (float)v;
    return (unsigned short)(__builtin_bit_cast(u32, f) >> 16);
}

__device__ __forceinline__ void gload16(const void* g, void* l) {
    __builtin_amdgcn_global_load_lds(
        (const __attribute__((address_space(1))) u32*)g,
        (__attribute__((address_space(3))) u32*)l, 16, 0, 0);
}

// ---------------- x fp32 -> bf16 ----------------
__global__ void k_cvt_x(const float* __restrict__ x, unsigned short* __restrict__ xb) {
    int i = (blockIdx.x * 256 + threadIdx.x) * 8;
    float4v a = *(const float4v*)(x + i);
    float4v b = *(const float4v*)(x + i + 4);
    ushort8 o;
    o[0] = bf16_rn(a[0]); o[1] = bf16_rn(a[1]); o[2] = bf16_rn(a[2]); o[3] = bf16_rn(a[3]);
    o[4] = bf16_rn(b[0]); o[5] = bf16_rn(b[1]); o[6] = bf16_rn(b[2]); o[7] = bf16_rn(b[3]);
    *(ushort8*)(xb + i) = o;
}

// ---------------- weight int32 -> bf16 ----------------
__global__ void k_cvt_w(const int* __restrict__ w, unsigned short* __restrict__ wb, int n) {
    int i = (blockIdx.x * 256 + threadIdx.x) * 8;
    if (i >= n) return;
    int4v a = *(const int4v*)(w + i);
    int4v b = *(const int4v*)(w + i + 4);
    ushort8 o;
    o[0] = bf16_from_int(a[0]); o[1] = bf16_from_int(a[1]);
    o[2] = bf16_from_int(a[2]); o[3] = bf16_from_int(a[3]);
    o[4] = bf16_from_int(b[0]); o[5] = bf16_from_int(b[1]);
    o[6] = bf16_from_int(b[2]); o[7] = bf16_from_int(b[3]);
    *(ushort8*)(wb + i) = o;
}

// ---------------- fused gate/up GEMM + silu*up -> h (bf16) ----------------
// C[m,f] for f-block of 128, m-block of 128. A = xb [NTOK][D_MODEL] bf16 (K-major)
// B = gate_w / up_w rows [D_FF][D_MODEL] (K-major, i.e. B^T GEMM).
template<bool BCVT>
__global__ __launch_bounds__(256, 2) void k_gateup(
    const unsigned short* __restrict__ xb,
    const void* __restrict__ gwp, const void* __restrict__ uwp,
    const float* __restrict__ gs, const float* __restrict__ us,
    unsigned short* __restrict__ h)
{
    __shared__ unsigned short As[128 * 32];
    __shared__ unsigned short Gs[128 * 32];
    __shared__ unsigned short Us[128 * 32];

    const int tid  = threadIdx.x;
    const int lane = tid & 63;
    const int wave = tid >> 6;          // 0..3
    const int wm   = wave >> 1;         // 0..1 (row half)
    const int wn   = wave & 1;          // 0..1 (col half)
    const int row0 = blockIdx.y * 128;
    const int col0 = blockIdx.x * 128;

    f32x4 accG[4][4], accU[4][4];
#pragma unroll
    for (int m = 0; m < 4; ++m)
#pragma unroll
        for (int n = 0; n < 4; ++n) {
            accG[m][n] = (f32x4){0.f, 0.f, 0.f, 0.f};
            accU[m][n] = (f32x4){0.f, 0.f, 0.f, 0.f};
        }

    const int arow = lane >> 2;         // 0..15 within a 16-row segment
    const int akk  = (lane & 3) * 8;    // k offset within 32 (units: elems)
    const int r    = lane & 15;
    const int kq   = (lane >> 4) * 8;

    for (int kt = 0; kt < D_MODEL / 32; ++kt) {
        const int k0 = kt * 32;
        __syncthreads();  // protect LDS from overwrite while prior compute reads

        // ---- stage A: 128x32 bf16 via global_load_lds (2 calls/wave) ----
#pragma unroll
        for (int j = 0; j < 2; ++j) {
            const int seg = j * 4 + wave;                 // 0..7, 512 elems each
            const unsigned short* g =
                xb + (size_t)(row0 + seg * 16 + arow) * D_MODEL + k0 + akk;
            gload16(g, &As[seg * 512]);
        }

        // ---- stage B tiles (gate & up) ----
        if constexpr (BCVT) {
            const int* gw = (const int*)gwp;
            const int* uw = (const int*)uwp;
#pragma unroll
            for (int it = 0; it < 2; ++it) {
                const int rowb = it * 64 + (tid >> 2);    // 0..127
                const int bkk  = (tid & 3) * 8;
                const size_t off = (size_t)(col0 + rowb) * D_MODEL + k0 + bkk;
                int4v g0 = *(const int4v*)(gw + off);
                int4v g1 = *(const int4v*)(gw + off + 4);
                int4v u0 = *(const int4v*)(uw + off);
                int4v u1 = *(const int4v*)(uw + off + 4);
                ushort8 og, ou;
#pragma unroll
                for (int e = 0; e < 4; ++e) {
                    og[e]     = bf16_from_int(g0[e]);
                    og[4 + e] = bf16_from_int(g1[e]);
                    ou[e]     = bf16_from_int(u0[e]);
                    ou[4 + e] = bf16_from_int(u1[e]);
                }
                *(ushort8*)&Gs[rowb * 32 + bkk] = og;
                *(ushort8*)&Us[rowb * 32 + bkk] = ou;
            }
        } else {
            const unsigned short* gw = (const unsigned short*)gwp;
            const unsigned short* uw = (const unsigned short*)uwp;
#pragma unroll
            for (int j = 0; j < 2; ++j) {
                const int seg = j * 4 + wave;
                const size_t off = (size_t)(col0 + seg * 16 + arow) * D_MODEL + k0 + akk;
                gload16(gw + off, &Gs[seg * 512]);
                gload16(uw + off, &Us[seg * 512]);
            }
        }
        __syncthreads();

        // ---- fragments + MFMA ----
        bf16x8 af[4], gf[4], uf[4];
#pragma unroll
        for (int m = 0; m < 4; ++m)
            af[m] = *(const bf16x8*)&As[(wm * 64 + m * 16 + r) * 32 + kq];
#pragma unroll
        for (int n = 0; n < 4; ++n) {
            gf[n] = *(const bf16x8*)&Gs[(wn * 64 + n * 16 + r) * 32 + kq];
            uf[n] = *(const bf16x8*)&Us[(wn * 64 + n * 16 + r) * 32 + kq];
        }
#pragma unroll
        for (int m = 0; m < 4; ++m)
#pragma unroll
            for (int n = 0; n < 4; ++n) {
                accG[m][n] = __builtin_amdgcn_mfma_f32_16x16x32_bf16(af[m], gf[n], accG[m][n], 0, 0, 0);
                accU[m][n] = __builtin_amdgcn_mfma_f32_16x16x32_bf16(af[m], uf[n], accU[m][n], 0, 0, 0);
            }
    }

    // ---- epilogue: silu(gate*gs) * (up*us) -> h bf16 ----
#pragma unroll
    for (int n = 0; n < 4; ++n) {
        const int col = col0 + wn * 64 + n * 16 + r;
        const float gsc = gs[col];
        const float usc = us[col];
#pragma unroll
        for (int m = 0; m < 4; ++m) {
            const int rowb = row0 + wm * 64 + m * 16 + (lane >> 4) * 4;
#pragma unroll
            for (int q = 0; q < 4; ++q) {
                float g = accG[m][n][q] * gsc;
                float u = accU[m][n][q] * usc;
                float sig = 1.0f / (1.0f + __expf(-g));
                h[(size_t)(rowb + q) * D_FF + col] = bf16_rn(g * sig * u);
            }
        }
    }
}

// ---------------- down GEMM: out[m,d] = (h @ down_w^T)[m,d] * ds[d] ----------------
template<bool BCVT>
__global__ __launch_bounds__(256, 2) void k_down(
    const unsigned short* __restrict__ hb,
    const void* __restrict__ dwp,
    const float* __restrict__ ds,
    float* __restrict__ out)
{
    __shared__ unsigned short As[128 * 32];
    __shared__ unsigned short Bs[128 * 32];

    const int tid  = threadIdx.x;
    const int lane = tid & 63;
    const int wave = tid >> 6;
    const int wm   = wave >> 1;
    const int wn   = wave & 1;
    const int row0 = blockIdx.y * 128;
    const int col0 = blockIdx.x * 128;

    f32x4 acc[4][4];
#pragma unroll
    for (int m = 0; m < 4; ++m)
#pragma unroll
        for (int n = 0; n < 4; ++n)
            acc[m][n] = (f32x4){0.f, 0.f, 0.f, 0.f};

    const int arow = lane >> 2;
    const int akk  = (lane & 3) * 8;
    const int r    = lane & 15;
    const int kq   = (lane >> 4) * 8;

    for (int kt = 0; kt < D_FF / 32; ++kt) {
        const int k0 = kt * 32;
        __syncthreads();

#pragma unroll
        for (int j = 0; j < 2; ++j) {
            const int seg = j * 4 + wave;
            const unsigned short* g =
                hb + (size_t)(row0 + seg * 16 + arow) * D_FF + k0 + akk;
            gload16(g, &As[seg * 512]);
        }

        if constexpr (BCVT) {
            const int* dw = (const int*)dwp;
#pragma unroll
            for (int it = 0; it < 2; ++it) {
                const int rowb = it * 64 + (tid >> 2);
                const int bkk  = (tid & 3) * 8;
                const size_t off = (size_t)(col0 + rowb) * D_FF + k0 + bkk;
                int4v w0 = *(const int4v*)(dw + off);
                int4v w1 = *(const int4v*)(dw + off + 4);
                ushort8 ow;
#pragma unroll
                for (int e = 0; e < 4; ++e) {
                    ow[e]     = bf16_from_int(w0[e]);
                    ow[4 + e] = bf16_from_int(w1[e]);
                }
                *(ushort8*)&Bs[rowb * 32 + bkk] = ow;
            }
        } else {
            const unsigned short* dw = (const unsigned short*)dwp;
#pragma unroll
            for (int j = 0; j < 2; ++j) {
                const int seg = j * 4 + wave;
                const size_t off = (size_t)(col0 + seg * 16 + arow) * D_FF + k0 + akk;
                gload16(dw + off, &Bs[seg * 512]);
            }
        }
        __syncthreads();

        bf16x8 af[4], bf[4];
#pragma unroll
        for (int m = 0; m < 4; ++m)
            af[m] = *(const bf16x8*)&As[(wm * 64 + m * 16 + r) * 32 + kq];
#pragma unroll
        for (int n = 0; n < 4; ++n)
            bf[n] = *(const bf16x8*)&Bs[(wn * 64 + n * 16 + r) * 32 + kq];
#pragma unroll
        for (int m = 0; m < 4; ++m)
#pragma unroll
            for (int n = 0; n < 4; ++n)
                acc[m][n] = __builtin_amdgcn_mfma_f32_16x16x32_bf16(af[m], bf[n], acc[m][n], 0, 0, 0);
    }

#pragma unroll
    for (int n = 0; n < 4; ++n) {
        const int col = col0 + wn * 64 + n * 16 + r;
        const float dsc = ds[col];
#pragma unroll
        for (int m = 0; m < 4; ++m) {
            const int rowb = row0 + wm * 64 + m * 16 + (lane >> 4) * 4;
#pragma unroll
            for (int q = 0; q < 4; ++q)
                out[(size_t)(rowb + q) * D_MODEL + col] = acc[m][n][q] * dsc;
        }
    }
}

extern "C" void kernel_launch(void* const* d_in, const int* in_sizes, int n_in,
                              void* d_out, int out_size, void* d_ws, size_t ws_size,
                              hipStream_t stream) {
    const float* x  = (const float*)d_in[0];
    const int*   gw = (const int*)d_in[1];
    const float* gs = (const float*)d_in[2];
    const int*   uw = (const int*)d_in[3];
    const float* us = (const float*)d_in[4];
    const int*   dw = (const int*)d_in[5];
    const float* ds = (const float*)d_in[6];
    float* out = (float*)d_out;

    const size_t XB = (size_t)NTOK * D_MODEL * 2;   // 33.5 MB  x bf16
    const size_t WB = (size_t)D_FF * D_MODEL * 2;   // 90.2 MB  per weight bf16
    const size_t HB = WB;                            // 90.2 MB  h bf16

    char* ws = (char*)d_ws;
    unsigned short* xb = (unsigned short*)ws;

    k_cvt_x<<<(NTOK * D_MODEL) / (8 * 256), 256, 0, stream>>>(x, xb);

    const int wn_elems = D_FF * D_MODEL;            // 45,088,768 (divisible by 2048)
    const int wgrid = wn_elems / (8 * 256);

    if (ws_size >= XB + 2 * WB + HB) {
        // Plan A: pre-convert weights -> pure-bf16 GEMMs with global_load_lds
        unsigned short* gwb = (unsigned short*)(ws + XB);
        unsigned short* uwb = (unsigned short*)(ws + XB + WB);
        unsigned short* hb  = (unsigned short*)(ws + XB + 2 * WB);
        k_cvt_w<<<wgrid, 256, 0, stream>>>(gw, gwb, wn_elems);
        k_cvt_w<<<wgrid, 256, 0, stream>>>(uw, uwb, wn_elems);
        k_gateup<false><<<dim3(D_FF / 128, NTOK / 128), 256, 0, stream>>>(
            xb, gwb, uwb, gs, us, hb);
        // reuse gate-weight region for down weights (stream-ordered)
        k_cvt_w<<<wgrid, 256, 0, stream>>>(dw, gwb, wn_elems);
        k_down<false><<<dim3(D_MODEL / 128, NTOK / 128), 256, 0, stream>>>(
            hb, gwb, ds, out);
    } else {
        // Plan B: convert weights in-GEMM (reg-staged)
        unsigned short* hb = (unsigned short*)(ws + XB);
        k_gateup<true><<<dim3(D_FF / 128, NTOK / 128), 256, 0, stream>>>(
            xb, gw, uw, gs, us, hb);
        k_down<true><<<dim3(D_MODEL / 128, NTOK / 128), 256, 0, stream>>>(
            hb, dw, ds, out);
    }
}

// Round 2
// 1258.211 us; speedup vs baseline: 1.3332x; 1.3332x over previous
//
#include <hip/hip_runtime.h>
#include <hip/hip_bf16.h>

#define D_MODEL 4096
#define D_FF    11008
#define NTOK    4096   // 2 * 2048 tokens

typedef unsigned int u32;
typedef unsigned short u16;
using f32x4   = __attribute__((ext_vector_type(4))) float;
using bf16x8  = __attribute__((ext_vector_type(8))) short;
using ushort8 = __attribute__((ext_vector_type(8))) unsigned short;
using int4v   = __attribute__((ext_vector_type(4))) int;
using float4v = __attribute__((ext_vector_type(4))) float;

__device__ __forceinline__ u16 bf16_rn(float f) {
    u32 u = __builtin_bit_cast(u32, f);
    u += 0x7FFFu + ((u >> 16) & 1u);
    return (u16)(u >> 16);
}
__device__ __forceinline__ u16 bf16_from_int(int v) {
    float f = (float)v;   // exact for |v| <= 127
    return (u16)(__builtin_bit_cast(u32, f) >> 16);
}
__device__ __forceinline__ float bf16_to_f(u16 b) {
    u32 u = (u32)b << 16;
    return __builtin_bit_cast(float, u);
}
__device__ __forceinline__ void gload16(const void* g, void* l) {
    __builtin_amdgcn_global_load_lds(
        (const __attribute__((address_space(1))) u32*)g,
        (__attribute__((address_space(3))) u32*)l, 16, 0, 0);
}

// ---------------- x fp32 -> bf16 ----------------
__global__ void k_cvt_x(const float* __restrict__ x, u16* __restrict__ xb) {
    int i = (blockIdx.x * 256 + threadIdx.x) * 8;
    float4v a = *(const float4v*)(x + i);
    float4v b = *(const float4v*)(x + i + 4);
    ushort8 o;
    o[0] = bf16_rn(a[0]); o[1] = bf16_rn(a[1]); o[2] = bf16_rn(a[2]); o[3] = bf16_rn(a[3]);
    o[4] = bf16_rn(b[0]); o[5] = bf16_rn(b[1]); o[6] = bf16_rn(b[2]); o[7] = bf16_rn(b[3]);
    *(ushort8*)(xb + i) = o;
}

// ---------------- weight int32 -> bf16 ----------------
__global__ void k_cvt_w(const int* __restrict__ w, u16* __restrict__ wb, int n) {
    int i = (blockIdx.x * 256 + threadIdx.x) * 8;
    if (i >= n) return;
    int4v a = *(const int4v*)(w + i);
    int4v b = *(const int4v*)(w + i + 4);
    ushort8 o;
    o[0] = bf16_from_int(a[0]); o[1] = bf16_from_int(a[1]);
    o[2] = bf16_from_int(a[2]); o[3] = bf16_from_int(a[3]);
    o[4] = bf16_from_int(b[0]); o[5] = bf16_from_int(b[1]);
    o[6] = bf16_from_int(b[2]); o[7] = bf16_from_int(b[3]);
    *(ushort8*)(wb + i) = o;
}

// =====================================================================
// 256x256 8-phase GEMM:  C = A[M][K] * (B[N][K])^T  (both bf16, K-major)
// 8 waves (2M x 4N), BK=64, double-buffered 128 KiB LDS, XOR-granule
// swizzle (g ^= row&7) on both stage-source and ds_read, counted vmcnt(6),
// setprio around MFMA clusters.
// EPI: 0 = obf[idx]  = bf16(acc*scale)              (gate)
//      1 = obf[idx]  = bf16(silu(g)*acc*scale), g read from obf (up+fuse)
//      2 = of32[idx] = acc*scale                    (down)
// =====================================================================

// LDS region offsets (ushort units): buf*32768 + {A:0,B:16384} + half*8192
#define REGA(BUF, H) ((BUF)*32768 + (H)*8192)
#define REGB(BUF, H) ((BUF)*32768 + 16384 + (H)*8192)

#define READA(AA, BUF, MH) { const int _b = REGA(BUF, MH) + aoff;             \
  _Pragma("unroll") for (int mm = 0; mm < 4; ++mm) {                          \
    AA[mm][0] = *(const bf16x8*)&lds[_b + mm*1024 + g0o];                     \
    AA[mm][1] = *(const bf16x8*)&lds[_b + mm*1024 + g1o]; } }

#define READB(BB, BUF, NH) { const int _b = REGB(BUF, NH) + boff;             \
  _Pragma("unroll") for (int nn = 0; nn < 2; ++nn) {                          \
    BB[nn][0] = *(const bf16x8*)&lds[_b + nn*1024 + g0o];                     \
    BB[nn][1] = *(const bf16x8*)&lds[_b + nn*1024 + g1o]; } }

#define MFMA16(MH, NH, AA, BB)                                                \
  _Pragma("unroll") for (int mm = 0; mm < 4; ++mm)                            \
  _Pragma("unroll") for (int nn = 0; nn < 2; ++nn)                            \
  _Pragma("unroll") for (int kk = 0; kk < 2; ++kk)                            \
    acc[(MH)*4+mm][(NH)*2+nn] = __builtin_amdgcn_mfma_f32_16x16x32_bf16(      \
        AA[mm][kk], BB[nn][kk], acc[(MH)*4+mm][(NH)*2+nn], 0, 0, 0);

#define STAGE_A(BUF, MH, K0) {                                                \
  const u16* _s = A + a_sbase + (size_t)(MH)*128*K + (K0);                    \
  gload16(_s,                &lds[REGA(BUF, MH) + wave*512]);                 \
  gload16(_s + (size_t)64*K, &lds[REGA(BUF, MH) + (8+wave)*512]); }

#define STAGE_B(BUF, NH, K0) {                                                \
  const u16* _s = B + b_sbase + (size_t)(NH)*128*K + (K0);                    \
  gload16(_s,                &lds[REGB(BUF, NH) + wave*512]);                 \
  gload16(_s + (size_t)64*K, &lds[REGB(BUF, NH) + (8+wave)*512]); }

#define PH_SYNC_PRE()  __builtin_amdgcn_s_barrier();                          \
  asm volatile("s_waitcnt lgkmcnt(0)" ::: "memory");                          \
  __builtin_amdgcn_sched_barrier(0);                                          \
  __builtin_amdgcn_s_setprio(1);

#define PH_SYNC_POST() __builtin_amdgcn_s_setprio(0);                         \
  __builtin_amdgcn_s_barrier();

template<int EPI>
__global__ __launch_bounds__(512, 2) void k_gemm256(
    const u16* __restrict__ A, const u16* __restrict__ B,
    const float* __restrict__ scale,
    u16* __restrict__ obf, float* __restrict__ of32,
    int K, int NBN, int ldc)
{
    __shared__ __align__(16) u16 lds[65536];   // 128 KiB

    const int tid  = threadIdx.x;
    const int lane = tid & 63;
    const int wave = tid >> 6;          // 0..7
    const int wm   = wave >> 2;         // 0..1
    const int wn   = wave & 3;          // 0..3

    // XCD-aware bijective swizzle (m204)
    const int nwg  = 16 * NBN;
    const int orig = blockIdx.x;
    const int qq   = nwg >> 3, rr = nwg & 7;
    const int xcd  = orig & 7;
    const int swz  = (xcd < rr ? xcd*(qq+1) : rr*(qq+1) + (xcd-rr)*qq) + (orig >> 3);
    const int bm   = swz & 15;          // M blocks = 4096/256 = 16
    const int bn   = swz >> 4;

    // fragment-read per-thread constants
    const int r    = lane & 15;
    const int sQ   = lane >> 4;         // 0..3
    const int x7   = r & 7;
    const int g0o  = (sQ ^ x7) * 8;             // kk=0 granule (ushort units)
    const int g1o  = ((4 | sQ) ^ x7) * 8;       // kk=1 granule
    const int aoff = (wm*64 + r) * 64;
    const int boff = (wn*32 + r) * 64;

    // stage per-thread constants (inverse swizzle on the global source)
    const int lrow = lane >> 3;                       // 0..7
    const int goff = ((lane & 7) ^ lrow) * 8;         // element offset in 64-col row
    const size_t a_sbase = (size_t)(bm*256 + wave*8 + lrow) * K + goff;
    const size_t b_sbase = (size_t)(bn*256 + wave*8 + lrow) * K + goff;

    f32x4 acc[8][4];
#pragma unroll
    for (int m = 0; m < 8; ++m)
#pragma unroll
        for (int n = 0; n < 4; ++n) acc[m][n] = (f32x4){0.f, 0.f, 0.f, 0.f};

    const int nt = K >> 6;              // K / 64

    // ---- prologue: tile0 {Ah0,Bh0,Bh1,Ah1} -> buf0 ; tile1 {Ah0,Bh0,Bh1} -> buf1
    STAGE_A(0, 0, 0);
    STAGE_B(0, 0, 0);
    STAGE_B(0, 1, 0);
    STAGE_A(0, 1, 0);
    STAGE_A(1, 0, 64);
    STAGE_B(1, 0, 64);
    STAGE_B(1, 1, 64);
    asm volatile("s_waitcnt vmcnt(6)" ::: "memory");
    __builtin_amdgcn_s_barrier();

    bf16x8 a[4][2], b0[2][2], b1[2][2];

    for (int t = 0; t < nt; ++t) {
        const int cur = t & 1, nxt = cur ^ 1;
        // ---- P1: quadrant (mh0, nh0); stage (t+1).Ah1 -> nxt
        READA(a, cur, 0);
        READB(b0, cur, 0);
        if (t + 1 < nt) STAGE_A(nxt, 1, (t+1) << 6);
        PH_SYNC_PRE();
        MFMA16(0, 0, a, b0);
        PH_SYNC_POST();
        // ---- P2: (mh0, nh1); stage (t+2).Ah0 -> cur
        READB(b1, cur, 1);
        if (t + 2 < nt) STAGE_A(cur, 0, (t+2) << 6);
        PH_SYNC_PRE();
        MFMA16(0, 1, a, b1);
        PH_SYNC_POST();
        // ---- P3: (mh1, nh1); stage (t+2).Bh0 -> cur
        READA(a, cur, 1);
        if (t + 2 < nt) STAGE_B(cur, 0, (t+2) << 6);
        PH_SYNC_PRE();
        MFMA16(1, 1, a, b1);
        PH_SYNC_POST();
        // ---- P4: (mh1, nh0) from held regs; stage (t+2).Bh1 -> cur; counted vmcnt
        if (t + 2 < nt) STAGE_B(cur, 1, (t+2) << 6);
        __builtin_amdgcn_s_barrier();
        __builtin_amdgcn_s_setprio(1);
        MFMA16(1, 0, a, b0);
        __builtin_amdgcn_s_setprio(0);
        if (t + 2 < nt) { asm volatile("s_waitcnt vmcnt(6)" ::: "memory"); }
        else            { asm volatile("s_waitcnt vmcnt(0)" ::: "memory"); }
        __builtin_amdgcn_s_barrier();
    }

    // ---- epilogue
#pragma unroll
    for (int n = 0; n < 4; ++n) {
        const int col = bn*256 + (n>>1)*128 + wn*32 + (n&1)*16 + r;
        const float sc = scale[col];
#pragma unroll
        for (int m = 0; m < 8; ++m) {
            const int row = bm*256 + (m>>2)*128 + wm*64 + (m&3)*16 + sQ*4;
#pragma unroll
            for (int q = 0; q < 4; ++q) {
                const float v = acc[m][n][q] * sc;
                const size_t idx = (size_t)(row + q) * ldc + col;
                if constexpr (EPI == 0) {
                    obf[idx] = bf16_rn(v);
                } else if constexpr (EPI == 1) {
                    const float g = bf16_to_f(obf[idx]);
                    const float s2 = g / (1.0f + __expf(-g));
                    obf[idx] = bf16_rn(s2 * v);
                } else {
                    of32[idx] = v;
                }
            }
        }
    }
}

extern "C" void kernel_launch(void* const* d_in, const int* in_sizes, int n_in,
                              void* d_out, int out_size, void* d_ws, size_t ws_size,
                              hipStream_t stream) {
    const float* x  = (const float*)d_in[0];
    const int*   gw = (const int*)d_in[1];
    const float* gs = (const float*)d_in[2];
    const int*   uw = (const int*)d_in[3];
    const float* us = (const float*)d_in[4];
    const int*   dw = (const int*)d_in[5];
    const float* ds = (const float*)d_in[6];
    float* out = (float*)d_out;

    const size_t XB = (size_t)NTOK * D_MODEL * 2;   // 33.5 MB  x bf16
    const size_t WB = (size_t)D_FF * D_MODEL * 2;   // 90.2 MB  weight bf16
    const size_t HB = WB;                           // 90.2 MB  g/h bf16
    if (ws_size < XB + WB + HB) return;             // loud failure (poisoned out)

    char* ws = (char*)d_ws;
    u16* xb   = (u16*)ws;
    u16* wb   = (u16*)(ws + XB);
    u16* gbuf = (u16*)(ws + XB + WB);

    const int wn_elems = D_FF * D_MODEL;            // 45,088,768
    const int wgrid = wn_elems / (8 * 256);

    k_cvt_x<<<(NTOK * D_MODEL) / (8 * 256), 256, 0, stream>>>(x, xb);

    // gate: g = bf16( (xb . gw^T) * gs )
    k_cvt_w<<<wgrid, 256, 0, stream>>>(gw, wb, wn_elems);
    k_gemm256<0><<<16 * (D_FF / 256), 512, 0, stream>>>(
        xb, wb, gs, gbuf, nullptr, D_MODEL, D_FF / 256, D_FF);

    // up + fuse: h = bf16( silu(g) * (xb . uw^T) * us )   (in-place into gbuf)
    k_cvt_w<<<wgrid, 256, 0, stream>>>(uw, wb, wn_elems);
    k_gemm256<1><<<16 * (D_FF / 256), 512, 0, stream>>>(
        xb, wb, us, gbuf, nullptr, D_MODEL, D_FF / 256, D_FF);

    // down: out = (h . dw^T) * ds   (fp32)
    k_cvt_w<<<wgrid, 256, 0, stream>>>(dw, wb, wn_elems);
    k_gemm256<2><<<16 * (D_MODEL / 256), 512, 0, stream>>>(
        gbuf, wb, ds, nullptr, out, D_FF, D_MODEL / 256, D_MODEL);
}

// Round 3
// 1237.457 us; speedup vs baseline: 1.3556x; 1.0168x over previous
//
#include <hip/hip_runtime.h>
#include <hip/hip_bf16.h>

#define D_MODEL 4096
#define D_FF    11008
#define NTOK    4096   // 2 * 2048 tokens

typedef unsigned int u32;
typedef unsigned short u16;
using f32x4   = __attribute__((ext_vector_type(4))) float;
using bf16x8  = __attribute__((ext_vector_type(8))) short;
using ushort8 = __attribute__((ext_vector_type(8))) unsigned short;
using int4v   = __attribute__((ext_vector_type(4))) int;
using float4v = __attribute__((ext_vector_type(4))) float;

__device__ __forceinline__ u16 bf16_rn(float f) {
    u32 u = __builtin_bit_cast(u32, f);
    u += 0x7FFFu + ((u >> 16) & 1u);
    return (u16)(u >> 16);
}
__device__ __forceinline__ u16 bf16_from_int(int v) {
    float f = (float)v;   // exact for |v| <= 127
    return (u16)(__builtin_bit_cast(u32, f) >> 16);
}
__device__ __forceinline__ float bf16_to_f(u16 b) {
    u32 u = (u32)b << 16;
    return __builtin_bit_cast(float, u);
}
__device__ __forceinline__ void gload16(const void* g, void* l) {
    __builtin_amdgcn_global_load_lds(
        (const __attribute__((address_space(1))) u32*)g,
        (__attribute__((address_space(3))) u32*)l, 16, 0, 0);
}

// ---------------- x fp32 -> bf16 ----------------
__global__ void k_cvt_x(const float* __restrict__ x, u16* __restrict__ xb) {
    int i = (blockIdx.x * 256 + threadIdx.x) * 8;
    float4v a = *(const float4v*)(x + i);
    float4v b = *(const float4v*)(x + i + 4);
    ushort8 o;
    o[0] = bf16_rn(a[0]); o[1] = bf16_rn(a[1]); o[2] = bf16_rn(a[2]); o[3] = bf16_rn(a[3]);
    o[4] = bf16_rn(b[0]); o[5] = bf16_rn(b[1]); o[6] = bf16_rn(b[2]); o[7] = bf16_rn(b[3]);
    *(ushort8*)(xb + i) = o;
}

// ---------------- weight int32 -> bf16 ----------------
__global__ void k_cvt_w(const int* __restrict__ w, u16* __restrict__ wb, int n) {
    int i = (blockIdx.x * 256 + threadIdx.x) * 8;
    if (i >= n) return;
    int4v a = *(const int4v*)(w + i);
    int4v b = *(const int4v*)(w + i + 4);
    ushort8 o;
    o[0] = bf16_from_int(a[0]); o[1] = bf16_from_int(a[1]);
    o[2] = bf16_from_int(a[2]); o[3] = bf16_from_int(a[3]);
    o[4] = bf16_from_int(b[0]); o[5] = bf16_from_int(b[1]);
    o[6] = bf16_from_int(b[2]); o[7] = bf16_from_int(b[3]);
    *(ushort8*)(wb + i) = o;
}

// =====================================================================
// 256x256 8-phase GEMM:  C = A[M][K] * (B[N][K])^T  (both bf16, K-major)
// 8 waves (2M x 4N), BK=64, double-buffered 128 KiB LDS, XOR-granule
// swizzle on both stage-source and ds_read, counted vmcnt(6), setprio.
// Fragment reads are INLINE-ASM ds_read_b128 (invisible to the waitcnt
// pass so the compiler cannot insert per-phase vmcnt(0) drains against
// the LDS-DMA writes); correctness is carried by the explicit protocol.
// EPI: 0 = obf[idx]  = bf16(acc*scale)              (gate)
//      1 = obf[idx]  = bf16(silu(g)*acc*scale), g read from obf (up+fuse)
//      2 = of32[idx] = acc*scale                    (down)
// =====================================================================

// LDS region offsets (ushort units): buf*32768 + {A:0,B:16384} + half*8192
#define REGA(BUF, H) ((BUF)*32768 + (H)*8192)
#define REGB(BUF, H) ((BUF)*32768 + 16384 + (H)*8192)

#define DSR(dst, addr, IMM)                                                   \
  asm volatile("ds_read_b128 %0, %1 offset:" #IMM : "=v"(dst) : "v"(addr))

#define READA(AA, BUF, MH) {                                                  \
  DSR(AA[0][0], aA[BUF][MH][0], 0);                                           \
  DSR(AA[0][1], aA[BUF][MH][1], 0);                                           \
  DSR(AA[1][0], aA[BUF][MH][0], 2048);                                        \
  DSR(AA[1][1], aA[BUF][MH][1], 2048);                                        \
  DSR(AA[2][0], aA[BUF][MH][0], 4096);                                        \
  DSR(AA[2][1], aA[BUF][MH][1], 4096);                                        \
  DSR(AA[3][0], aA[BUF][MH][0], 6144);                                        \
  DSR(AA[3][1], aA[BUF][MH][1], 6144); }

#define READB(BB, BUF, NH) {                                                  \
  DSR(BB[0][0], aB[BUF][NH][0], 0);                                           \
  DSR(BB[0][1], aB[BUF][NH][1], 0);                                           \
  DSR(BB[1][0], aB[BUF][NH][0], 2048);                                        \
  DSR(BB[1][1], aB[BUF][NH][1], 2048); }

#define MFMA16(MH, NH, AA, BB)                                                \
  _Pragma("unroll") for (int mm = 0; mm < 4; ++mm)                            \
  _Pragma("unroll") for (int nn = 0; nn < 2; ++nn)                            \
  _Pragma("unroll") for (int kk = 0; kk < 2; ++kk)                            \
    acc[(MH)*4+mm][(NH)*2+nn] = __builtin_amdgcn_mfma_f32_16x16x32_bf16(      \
        AA[mm][kk], BB[nn][kk], acc[(MH)*4+mm][(NH)*2+nn], 0, 0, 0);

#define STAGE_A(BUF, MH, K0) {                                                \
  const u16* _s = A + a_sbase + (size_t)(MH)*128*K + (K0);                    \
  gload16(_s,                &lds[REGA(BUF, MH) + wave*512]);                 \
  gload16(_s + (size_t)64*K, &lds[REGA(BUF, MH) + (8+wave)*512]); }

#define STAGE_B(BUF, NH, K0) {                                                \
  const u16* _s = B + b_sbase + (size_t)(NH)*128*K + (K0);                    \
  gload16(_s,                &lds[REGB(BUF, NH) + wave*512]);                 \
  gload16(_s + (size_t)64*K, &lds[REGB(BUF, NH) + (8+wave)*512]); }

#define PH_SYNC_PRE()  __builtin_amdgcn_s_barrier();                          \
  asm volatile("s_waitcnt lgkmcnt(0)" ::: "memory");                          \
  __builtin_amdgcn_sched_barrier(0);                                          \
  __builtin_amdgcn_s_setprio(1);

#define PH_SYNC_POST() __builtin_amdgcn_s_setprio(0);                         \
  __builtin_amdgcn_s_barrier();

#define TILE(CUR, NXT, T) {                                                   \
    /* P1: (mh0,nh0); stage (T+1).Ah1 -> NXT */                               \
    READA(a, CUR, 0); READB(b0, CUR, 0);                                      \
    if ((T) + 1 < nt) STAGE_A(NXT, 1, ((T)+1) << 6);                          \
    PH_SYNC_PRE(); MFMA16(0, 0, a, b0); PH_SYNC_POST();                       \
    /* P2: (mh0,nh1); stage (T+2).Ah0 -> CUR */                               \
    READB(b1, CUR, 1);                                                        \
    if ((T) + 2 < nt) STAGE_A(CUR, 0, ((T)+2) << 6);                          \
    PH_SYNC_PRE(); MFMA16(0, 1, a, b1); PH_SYNC_POST();                       \
    /* P3: (mh1,nh1); stage (T+2).Bh0 -> CUR */                               \
    READA(a, CUR, 1);                                                         \
    if ((T) + 2 < nt) STAGE_B(CUR, 0, ((T)+2) << 6);                          \
    PH_SYNC_PRE(); MFMA16(1, 1, a, b1); PH_SYNC_POST();                       \
    /* P4: (mh1,nh0) from held regs; stage (T+2).Bh1 -> CUR; counted vmcnt */ \
    if ((T) + 2 < nt) STAGE_B(CUR, 1, ((T)+2) << 6);                          \
    __builtin_amdgcn_s_barrier();                                             \
    __builtin_amdgcn_s_setprio(1);                                            \
    MFMA16(1, 0, a, b0);                                                      \
    __builtin_amdgcn_s_setprio(0);                                            \
    if ((T) + 2 < nt) { asm volatile("s_waitcnt vmcnt(6)" ::: "memory"); }    \
    else              { asm volatile("s_waitcnt vmcnt(0)" ::: "memory"); }    \
    __builtin_amdgcn_s_barrier(); }

template<int EPI>
__global__ __launch_bounds__(512, 2) void k_gemm256(
    const u16* __restrict__ A, const u16* __restrict__ B,
    const float* __restrict__ scale,
    u16* __restrict__ obf, float* __restrict__ of32,
    int K, int NBN, int ldc)
{
    __shared__ __align__(16) u16 lds[65536];   // 128 KiB

    const int tid  = threadIdx.x;
    const int lane = tid & 63;
    const int wave = tid >> 6;          // 0..7
    const int wm   = wave >> 2;         // 0..1
    const int wn   = wave & 3;          // 0..3

    // XCD-aware bijective swizzle (m204)
    const int nwg  = 16 * NBN;
    const int orig = blockIdx.x;
    const int qq   = nwg >> 3, rr = nwg & 7;
    const int xcd  = orig & 7;
    const int swz  = (xcd < rr ? xcd*(qq+1) : rr*(qq+1) + (xcd-rr)*qq) + (orig >> 3);
    const int bm   = swz & 15;          // M blocks = 4096/256 = 16
    const int bn   = swz >> 4;

    // fragment-read per-thread constants
    const int r    = lane & 15;
    const int sQ   = lane >> 4;         // 0..3
    const int x7   = r & 7;
    const int g0o  = (sQ ^ x7) * 8;             // kk=0 granule (ushort units)
    const int g1o  = ((4 | sQ) ^ x7) * 8;       // kk=1 granule
    const int aoff = (wm*64 + r) * 64;
    const int boff = (wn*32 + r) * 64;

    // precomputed as(3) byte addresses for all buf/half/granule combos
    const u32 lbase = (u32)(uintptr_t)(__attribute__((address_space(3))) u16*)&lds[0];
    u32 aA[2][2][2], aB[2][2][2];
#pragma unroll
    for (int bu = 0; bu < 2; ++bu)
#pragma unroll
        for (int h = 0; h < 2; ++h) {
            aA[bu][h][0] = lbase + (u32)(REGA(bu, h) + aoff + g0o) * 2;
            aA[bu][h][1] = lbase + (u32)(REGA(bu, h) + aoff + g1o) * 2;
            aB[bu][h][0] = lbase + (u32)(REGB(bu, h) + boff + g0o) * 2;
            aB[bu][h][1] = lbase + (u32)(REGB(bu, h) + boff + g1o) * 2;
        }

    // stage per-thread constants (inverse swizzle on the global source)
    const int lrow = lane >> 3;                       // 0..7
    const int goff = ((lane & 7) ^ lrow) * 8;         // element offset in 64-col row
    const size_t a_sbase = (size_t)(bm*256 + wave*8 + lrow) * K + goff;
    const size_t b_sbase = (size_t)(bn*256 + wave*8 + lrow) * K + goff;

    f32x4 acc[8][4];
#pragma unroll
    for (int m = 0; m < 8; ++m)
#pragma unroll
        for (int n = 0; n < 4; ++n) acc[m][n] = (f32x4){0.f, 0.f, 0.f, 0.f};

    const int nt = K >> 6;              // K / 64 (even for K=4096 and 11008)

    // ---- prologue: tile0 {Ah0,Bh0,Bh1,Ah1} -> buf0 ; tile1 {Ah0,Bh0,Bh1} -> buf1
    STAGE_A(0, 0, 0);
    STAGE_B(0, 0, 0);
    STAGE_B(0, 1, 0);
    STAGE_A(0, 1, 0);
    STAGE_A(1, 0, 64);
    STAGE_B(1, 0, 64);
    STAGE_B(1, 1, 64);
    asm volatile("s_waitcnt vmcnt(6)" ::: "memory");
    __builtin_amdgcn_s_barrier();

    bf16x8 a[4][2], b0[2][2], b1[2][2];

    for (int t = 0; t < nt; t += 2) {
        TILE(0, 1, t);
        TILE(1, 0, t + 1);
    }

    // ---- epilogue
#pragma unroll
    for (int n = 0; n < 4; ++n) {
        const int col = bn*256 + (n>>1)*128 + wn*32 + (n&1)*16 + r;
        const float sc = scale[col];
#pragma unroll
        for (int m = 0; m < 8; ++m) {
            const int row = bm*256 + (m>>2)*128 + wm*64 + (m&3)*16 + sQ*4;
#pragma unroll
            for (int q = 0; q < 4; ++q) {
                const float v = acc[m][n][q] * sc;
                const size_t idx = (size_t)(row + q) * ldc + col;
                if constexpr (EPI == 0) {
                    obf[idx] = bf16_rn(v);
                } else if constexpr (EPI == 1) {
                    const float g = bf16_to_f(obf[idx]);
                    const float s2 = g / (1.0f + __expf(-g));
                    obf[idx] = bf16_rn(s2 * v);
                } else {
                    of32[idx] = v;
                }
            }
        }
    }
}

extern "C" void kernel_launch(void* const* d_in, const int* in_sizes, int n_in,
                              void* d_out, int out_size, void* d_ws, size_t ws_size,
                              hipStream_t stream) {
    const float* x  = (const float*)d_in[0];
    const int*   gw = (const int*)d_in[1];
    const float* gs = (const float*)d_in[2];
    const int*   uw = (const int*)d_in[3];
    const float* us = (const float*)d_in[4];
    const int*   dw = (const int*)d_in[5];
    const float* ds = (const float*)d_in[6];
    float* out = (float*)d_out;

    const size_t XB = (size_t)NTOK * D_MODEL * 2;   // 33.5 MB  x bf16
    const size_t WB = (size_t)D_FF * D_MODEL * 2;   // 90.2 MB  weight bf16
    const size_t HB = WB;                           // 90.2 MB  g/h bf16
    if (ws_size < XB + WB + HB) return;             // loud failure (poisoned out)

    char* ws = (char*)d_ws;
    u16* xb   = (u16*)ws;
    u16* wb   = (u16*)(ws + XB);
    u16* gbuf = (u16*)(ws + XB + WB);

    const int wn_elems = D_FF * D_MODEL;            // 45,088,768
    const int wgrid = wn_elems / (8 * 256);

    k_cvt_x<<<(NTOK * D_MODEL) / (8 * 256), 256, 0, stream>>>(x, xb);

    // gate: g = bf16( (xb . gw^T) * gs )
    k_cvt_w<<<wgrid, 256, 0, stream>>>(gw, wb, wn_elems);
    k_gemm256<0><<<16 * (D_FF / 256), 512, 0, stream>>>(
        xb, wb, gs, gbuf, nullptr, D_MODEL, D_FF / 256, D_FF);

    // up + fuse: h = bf16( silu(g) * (xb . uw^T) * us )   (in-place into gbuf)
    k_cvt_w<<<wgrid, 256, 0, stream>>>(uw, wb, wn_elems);
    k_gemm256<1><<<16 * (D_FF / 256), 512, 0, stream>>>(
        xb, wb, us, gbuf, nullptr, D_MODEL, D_FF / 256, D_FF);

    // down: out = (h . dw^T) * ds   (fp32)
    k_cvt_w<<<wgrid, 256, 0, stream>>>(dw, wb, wn_elems);
    k_gemm256<2><<<16 * (D_MODEL / 256), 512, 0, stream>>>(
        gbuf, wb, ds, nullptr, out, D_FF, D_MODEL / 256, D_MODEL);
}